// Round 1
// baseline (392.406 us; speedup 1.0000x reference)
//
#include <hip/hip_runtime.h>

// GatedAttentionUnit: B=4, S=2048, D=768, I=1536, H=128, bf16 MFMA pipeline.
// Pipeline: cvt x->bf16; transpose+cvt weights; bias table;
//  G1: vt[b][i][s]  = silu(x@vW+vb)^T            (store transposed)
//  G2: gate[bs][i]  = silu(x@gW+gb)              (computed transposed)
//  G3: q,k[bs][h]   = silu(x@inW+inb)*gamma+beta (computed transposed)
//  SC: P[b][s][s']  = relu(q.k/sqrt(I)+bias)^2, causal, bf16 (block-skip upper tri)
//  G4: og[bs][i]    = (P@v)*gate                 (computed transposed, K clamped to causal extent)
//  G5: out[bs][d]   = og@outW + ob  (fp32)       (computed transposed)

typedef short short8 __attribute__((ext_vector_type(8)));
typedef float f32x4 __attribute__((ext_vector_type(4)));
typedef unsigned short us4 __attribute__((ext_vector_type(4)));
typedef float fl4 __attribute__((ext_vector_type(4)));

#define BM 128
#define BN 128
#define BK 64

enum { EPI_VT = 0, EPI_GATE = 1, EPI_QK = 2, EPI_SCORES = 3, EPI_OG = 4, EPI_OUT = 5 };

__device__ __forceinline__ unsigned short f2bf(float f) {
  unsigned u = __builtin_bit_cast(unsigned, f);
  u += 0x7FFFu + ((u >> 16) & 1u);
  return (unsigned short)(u >> 16);
}
__device__ __forceinline__ float bf2f(unsigned short b) {
  return __builtin_bit_cast(float, ((unsigned)b) << 16);
}
__device__ __forceinline__ float silu_f(float x) { return x / (1.0f + __expf(-x)); }

// ---- global -> LDS async staging: 128x64 bf16 tile (16 KB), 4 calls/wave x 16B/lane
__device__ __forceinline__ void stage_tile(const unsigned short* __restrict__ g,
                                           int row_stride, int r0, int ko,
                                           unsigned short* lds, int w, int l) {
#pragma unroll
  for (int c = 0; c < 4; ++c) {
    int e = ((w * 4 + c) << 9) + l * 8;  // element index in LDS tile
    int row = e >> 6;
    int kk = e & 63;
    const unsigned short* gp = g + (size_t)(r0 + row) * row_stride + (ko + kk);
    unsigned short* lp = lds + e;  // = wave-uniform base + lane*16B
    __builtin_amdgcn_global_load_lds((const __attribute__((address_space(1))) void*)gp,
                                     (__attribute__((address_space(3))) void*)lp,
                                     16, 0, 0);
  }
}

template <int EPI>
__global__ __launch_bounds__(256) void gemm_k(
    const unsigned short* __restrict__ A,   // M x K row-major bf16
    const unsigned short* __restrict__ Bt,  // N x K row-major bf16 (B^T)
    char* __restrict__ out0, char* __restrict__ out1,
    const float* __restrict__ f0, const float* __restrict__ f1,
    const float* __restrict__ f2, const float* __restrict__ f3,
    const float* __restrict__ f4,
    const unsigned short* __restrict__ aux,
    const float* __restrict__ bias_tab,
    int K,
    long long az, long long btz, long long ozb, long long auxz,
    int kclamp) {
  __shared__ unsigned short As[BM * BK];
  __shared__ unsigned short Bs[BN * BK];

  const int t = threadIdx.x;
  const int l = t & 63;
  const int w = t >> 6;
  const int m0 = blockIdx.y * BM;
  const int n0 = blockIdx.x * BN;
  const int z = blockIdx.z;

  A += (size_t)z * az;
  Bt += (size_t)z * btz;
  out0 += (size_t)z * ozb;
  aux += (size_t)z * auxz;

  const int wm = (w >> 1) * 64;
  const int wn = (w & 1) * 64;
  const int quad = l >> 4;
  const int lr = quad * 4;
  const int lc = l & 15;

  f32x4 acc[4][4] = {};

  const bool zero_block = (EPI == EPI_SCORES) && (m0 > n0 + BN - 1);
  const int kend = kclamp ? ((K < n0 + BN) ? K : (n0 + BN)) : K;

  if (!zero_block) {
    for (int ko = 0; ko < kend; ko += BK) {
      stage_tile(A, K, m0, ko, As, w, l);
      stage_tile(Bt, K, n0, ko, Bs, w, l);
      __syncthreads();
#pragma unroll
      for (int kk = 0; kk < 2; ++kk) {
        short8 af[4], bfr[4];
#pragma unroll
        for (int i = 0; i < 4; ++i)
          af[i] = *(const short8*)&As[(wm + i * 16 + lc) * BK + kk * 32 + quad * 8];
#pragma unroll
        for (int j = 0; j < 4; ++j)
          bfr[j] = *(const short8*)&Bs[(wn + j * 16 + lc) * BK + kk * 32 + quad * 8];
#pragma unroll
        for (int i = 0; i < 4; ++i)
#pragma unroll
          for (int j = 0; j < 4; ++j)
            acc[i][j] = __builtin_amdgcn_mfma_f32_16x16x32_bf16(af[i], bfr[j], acc[i][j], 0, 0, 0);
      }
      __syncthreads();
    }
  }

  // Epilogue: per lane, per 16x16 tile: 4 values at rows gm..gm+3, col gn.
  // "Transposed store": output[gn][gm..gm+3] are consecutive.
#pragma unroll
  for (int i = 0; i < 4; ++i) {
    const int gm = m0 + wm + i * 16 + lr;
#pragma unroll
    for (int j = 0; j < 4; ++j) {
      const int gn = n0 + wn + j * 16 + lc;
      f32x4 a = acc[i][j];
      if constexpr (EPI == EPI_VT) {
        // C = v (M=BS, N=I). Store vt[b][n][s], 4 consecutive s.
        float bn_ = f0[gn];
        us4 pk;
#pragma unroll
        for (int r = 0; r < 4; ++r) pk[r] = f2bf(silu_f(a[r] + bn_));
        size_t off = (size_t)(gm >> 11) * (1536 * 2048) + (size_t)gn * 2048 + (gm & 2047);
        *(us4*)((unsigned short*)out0 + off) = pk;
      } else if constexpr (EPI == EPI_GATE) {
        // C = gate^T (M=I, N=BS). Store gate[gn][gm..gm+3] row-major.
        fl4 bv = *(const fl4*)&f0[gm];
        us4 pk;
#pragma unroll
        for (int r = 0; r < 4; ++r) pk[r] = f2bf(silu_f(a[r] + bv[r]));
        *(us4*)((unsigned short*)out0 + (size_t)gn * 1536 + gm) = pk;
      } else if constexpr (EPI == EPI_QK) {
        // C = base^T (M=H=128, N=BS). q/k row-major [BS][128].
        fl4 bb = *(const fl4*)&f0[gm];
        fl4 qg = *(const fl4*)&f1[gm];
        fl4 qb = *(const fl4*)&f2[gm];
        fl4 kg = *(const fl4*)&f3[gm];
        fl4 kb = *(const fl4*)&f4[gm];
        us4 pq, pk2;
#pragma unroll
        for (int r = 0; r < 4; ++r) {
          float s = silu_f(a[r] + bb[r]);
          pq[r] = f2bf(s * qg[r] + qb[r]);
          pk2[r] = f2bf(s * kg[r] + kb[r]);
        }
        *(us4*)((unsigned short*)out0 + (size_t)gn * 128 + gm) = pq;
        *(us4*)((unsigned short*)out1 + (size_t)gn * 128 + gm) = pk2;
      } else if constexpr (EPI == EPI_SCORES) {
        // C[m=s'][n=s] = k.q ; P[s][s'] = relu(C*scale + bias[s-s'])^2 if s'<=s else 0
        const float SCALE = 0.025515518153991442f;  // 1/sqrt(1536)
        us4 pk;
#pragma unroll
        for (int r = 0; r < 4; ++r) {
          int mm = gm + r;
          float v = 0.0f;
          if (mm <= gn) {
            float tt = fmaf(a[r], SCALE, bias_tab[gn - mm]);
            tt = fmaxf(tt, 0.0f);
            v = tt * tt;
          }
          pk[r] = f2bf(v);
        }
        *(us4*)((unsigned short*)out0 + (size_t)gn * 2048 + gm) = pk;
      } else if constexpr (EPI == EPI_OG) {
        // C = og^T (M=I, N=S per batch). og[bs][i] = o * gate.
        us4 g4 = *(const us4*)&aux[(size_t)gn * 1536 + gm];
        us4 pk;
#pragma unroll
        for (int r = 0; r < 4; ++r) pk[r] = f2bf(a[r] * bf2f(g4[r]));
        *(us4*)((unsigned short*)out0 + (size_t)gn * 1536 + gm) = pk;
      } else {  // EPI_OUT
        // C = out^T (M=D=768, N=BS). d_out[gn][gm..gm+3] float4.
        fl4 ob = *(const fl4*)&f0[gm];
        fl4 res;
#pragma unroll
        for (int r = 0; r < 4; ++r) res[r] = a[r] + ob[r];
        *(fl4*)((float*)out0 + (size_t)gn * 768 + gm) = res;
      }
    }
  }
}

__global__ void cvt_bf16(const float* __restrict__ in, unsigned short* __restrict__ out, int n) {
  int i = (blockIdx.x * blockDim.x + threadIdx.x) * 4;
  if (i < n) {
    fl4 v = *(const fl4*)&in[i];
    us4 o;
#pragma unroll
    for (int r = 0; r < 4; ++r) o[r] = f2bf(v[r]);
    *(us4*)&out[i] = o;
  }
}

// out[n][k] = bf16(in[k][n]); dims multiples of 32.
__global__ void transpose_cvt(const float* __restrict__ in, unsigned short* __restrict__ out,
                              int K_, int N_) {
  __shared__ float tile[32][33];
  int bn = blockIdx.x * 32;
  int bk = blockIdx.y * 32;
  int tx = threadIdx.x, ty = threadIdx.y;
#pragma unroll
  for (int i2 = 0; i2 < 32; i2 += 8)
    tile[ty + i2][tx] = in[(size_t)(bk + ty + i2) * N_ + (bn + tx)];
  __syncthreads();
#pragma unroll
  for (int i2 = 0; i2 < 32; i2 += 8)
    out[(size_t)(bn + ty + i2) * K_ + (bk + tx)] = f2bf(tile[tx][ty + i2]);
}

// T5 relative position bias table: tab[d] = rel_emb[bucket(d)] * sqrt(128)
__global__ void build_bias(const float* __restrict__ rel_emb, float* __restrict__ tab) {
  int d = blockIdx.x * blockDim.x + threadIdx.x;
  if (d < 2048) {
    int bucket;
    if (d < 16) {
      bucket = d;
    } else {
      float n = (float)d;
      int vl = 16 + (int)((logf(n * 0.0625f) / logf(8.0f)) * 16.0f);
      bucket = vl < 31 ? vl : 31;
    }
    tab[d] = rel_emb[bucket] * 11.3137085f;  // fp32(np.sqrt(128))
  }
}

extern "C" void kernel_launch(void* const* d_in, const int* in_sizes, int n_in,
                              void* d_out, int out_size, void* d_ws, size_t ws_size,
                              hipStream_t stream) {
  const float* x    = (const float*)d_in[0];
  const float* vW   = (const float*)d_in[1];
  const float* v_b  = (const float*)d_in[2];
  const float* gW   = (const float*)d_in[3];
  const float* g_b  = (const float*)d_in[4];
  const float* inW  = (const float*)d_in[5];
  const float* in_b = (const float*)d_in[6];
  const float* q_g  = (const float*)d_in[7];
  const float* q_be = (const float*)d_in[8];
  const float* k_g  = (const float*)d_in[9];
  const float* k_be = (const float*)d_in[10];
  const float* oW   = (const float*)d_in[11];
  const float* o_b  = (const float*)d_in[12];
  const float* rel  = (const float*)d_in[13];

  char* p = (char*)d_ws;
  auto alloc = [&](size_t bytes) -> char* {
    char* r = p;
    p += (bytes + 255) & ~(size_t)255;
    return r;
  };
  unsigned short* x_bf = (unsigned short*)alloc(8192ull * 768 * 2);
  unsigned short* vWt  = (unsigned short*)alloc(1536ull * 768 * 2);
  unsigned short* gWt  = (unsigned short*)alloc(1536ull * 768 * 2);
  unsigned short* inWt = (unsigned short*)alloc(128ull * 768 * 2);
  unsigned short* oWt  = (unsigned short*)alloc(768ull * 1536 * 2);
  unsigned short* wq   = (unsigned short*)alloc(8192ull * 128 * 2);
  unsigned short* wk   = (unsigned short*)alloc(8192ull * 128 * 2);
  unsigned short* vt   = (unsigned short*)alloc(4ull * 1536 * 2048 * 2);
  unsigned short* gate = (unsigned short*)alloc(8192ull * 1536 * 2);
  unsigned short* P    = (unsigned short*)alloc(4ull * 2048 * 2048 * 2);
  unsigned short* og   = (unsigned short*)alloc(8192ull * 1536 * 2);
  float* btab          = (float*)alloc(2048 * 4);
  // total ~127 MB

  cvt_bf16<<<dim3(6144), dim3(256), 0, stream>>>(x, x_bf, 8192 * 768);
  dim3 tb(32, 8);
  transpose_cvt<<<dim3(48, 24), tb, 0, stream>>>(vW, vWt, 768, 1536);
  transpose_cvt<<<dim3(48, 24), tb, 0, stream>>>(gW, gWt, 768, 1536);
  transpose_cvt<<<dim3(4, 24), tb, 0, stream>>>(inW, inWt, 768, 128);
  transpose_cvt<<<dim3(24, 48), tb, 0, stream>>>(oW, oWt, 1536, 768);
  build_bias<<<dim3(8), dim3(256), 0, stream>>>(rel, btab);

  // G1: v^T staged out. A=x (8192x768), Bt=vW^T (1536x768). M=8192,N=1536.
  gemm_k<EPI_VT><<<dim3(12, 64, 1), 256, 0, stream>>>(
      x_bf, vWt, (char*)vt, nullptr, v_b, nullptr, nullptr, nullptr, nullptr,
      nullptr, nullptr, 768, 0, 0, 0, 0, 0);
  // G2: gate^T. A=gW^T (1536x768), Bt=x. M=1536,N=8192.
  gemm_k<EPI_GATE><<<dim3(64, 12, 1), 256, 0, stream>>>(
      gWt, x_bf, (char*)gate, nullptr, g_b, nullptr, nullptr, nullptr, nullptr,
      nullptr, nullptr, 768, 0, 0, 0, 0, 0);
  // G3: base^T -> q,k. A=inW^T (128x768), Bt=x. M=128,N=8192.
  gemm_k<EPI_QK><<<dim3(64, 1, 1), 256, 0, stream>>>(
      inWt, x_bf, (char*)wq, (char*)wk, in_b, q_g, q_be, k_g, k_be,
      nullptr, nullptr, 768, 0, 0, 0, 0, 0);
  // Scores: per batch, C = k@q^T (M=N=2048,K=128) -> P row-major.
  gemm_k<EPI_SCORES><<<dim3(16, 16, 4), 256, 0, stream>>>(
      wk, wq, (char*)P, nullptr, nullptr, nullptr, nullptr, nullptr, nullptr,
      nullptr, btab, 128, 2048ll * 128, 2048ll * 128, 2048ll * 2048 * 2, 0, 0);
  // G4: og^T = v^T @ P^T, x gate. A=vt[b] (1536x2048), Bt=P[b] (2048x2048). K clamped causal.
  gemm_k<EPI_OG><<<dim3(16, 12, 4), 256, 0, stream>>>(
      vt, P, (char*)og, nullptr, nullptr, nullptr, nullptr, nullptr, nullptr,
      gate, nullptr, 2048, 1536ll * 2048, 2048ll * 2048, 2048ll * 1536 * 2, 2048ll * 1536, 1);
  // G5: out^T. A=outW^T (768x1536), Bt=og (8192x1536). fp32 out + bias.
  gemm_k<EPI_OUT><<<dim3(64, 6, 1), 256, 0, stream>>>(
      oWt, og, (char*)d_out, nullptr, o_b, nullptr, nullptr, nullptr, nullptr,
      nullptr, nullptr, 1536, 0, 0, 0, 0, 0);
}

// Round 2
// 336.960 us; speedup vs baseline: 1.1645x; 1.1645x over previous
//
#include <hip/hip_runtime.h>

// GatedAttentionUnit: B=4, S=2048, D=768, I=1536, H=128, bf16 MFMA pipeline.
//  prep: cvt x->bf16; 4 weight transposes (1 launch); bias table
//  G1 : vt[b][i][s]  = silu(x@vW+vb)^T           (store transposed)
//  G23: gate[bs][i]  = silu(x@gW+gb)  +  q,k[bs][h] (merged launch, y==12 -> qk)
//  SC : P[b][s][s']  = relu(q.k/sqrt(I)+bias)^2, causal, bf16 (triangular grid only)
//  OG : og[bs][i]    = (P@v)*gate   -- balanced pair-tiles (n0, 15-n0), 64x128 blocks
//  G5 : out[bs][d]   = og@outW + ob  (fp32)

typedef short short8 __attribute__((ext_vector_type(8)));
typedef float f32x4 __attribute__((ext_vector_type(4)));
typedef unsigned short us4 __attribute__((ext_vector_type(4)));
typedef float fl4 __attribute__((ext_vector_type(4)));

#define BM 128
#define BN 128
#define BK 64

enum { EPI_VT = 0, EPI_GQK = 1, EPI_SCORES = 3, EPI_OUT = 5 };

__device__ __forceinline__ unsigned short f2bf(float f) {
  unsigned u = __builtin_bit_cast(unsigned, f);
  u += 0x7FFFu + ((u >> 16) & 1u);
  return (unsigned short)(u >> 16);
}
__device__ __forceinline__ float bf2f(unsigned short b) {
  return __builtin_bit_cast(float, ((unsigned)b) << 16);
}
__device__ __forceinline__ float silu_f(float x) { return x / (1.0f + __expf(-x)); }

__device__ __forceinline__ void gl_lds(const unsigned short* gp, unsigned short* lp) {
  __builtin_amdgcn_global_load_lds((const __attribute__((address_space(1))) void*)gp,
                                   (__attribute__((address_space(3))) void*)lp, 16, 0, 0);
}

// global -> LDS async staging: 128x64 bf16 tile, 4 calls/wave x 16B/lane
__device__ __forceinline__ void stage_tile(const unsigned short* __restrict__ g,
                                           int row_stride, int r0, int ko,
                                           unsigned short* lds, int w, int l) {
#pragma unroll
  for (int c = 0; c < 4; ++c) {
    int e = ((w * 4 + c) << 9) + l * 8;
    int row = e >> 6;
    int kk = e & 63;
    gl_lds(g + (size_t)(r0 + row) * row_stride + (ko + kk), lds + e);
  }
}

template <int EPI>
__global__ __launch_bounds__(256) void gemm_k(
    const unsigned short* __restrict__ A,   // M x K row-major bf16
    const unsigned short* __restrict__ Bt,  // N x K row-major bf16 (B^T)
    char* __restrict__ out0, char* __restrict__ out1, char* __restrict__ out2,
    const float* __restrict__ f0, const float* __restrict__ f1,
    const float* __restrict__ f2, const float* __restrict__ f3,
    const float* __restrict__ f4, const float* __restrict__ f5,
    const unsigned short* __restrict__ A2,
    const float* __restrict__ bias_tab,
    int K, long long az, long long btz, long long ozb) {
  __shared__ unsigned short As[BM * BK];
  __shared__ unsigned short Bs[BN * BK];

  const int t = threadIdx.x;
  const int l = t & 63;
  const int w = t >> 6;
  const int z = blockIdx.z;

  bool qk = false;
  int m0, n0;
  if constexpr (EPI == EPI_SCORES) {
    // triangular tile decode: t -> (r, c), c <= r. m0 = s' tile, n0 = s tile.
    int ti = blockIdx.x;
    int r = (int)((sqrtf((float)(8 * ti + 1)) - 1.0f) * 0.5f);
    if ((r + 1) * (r + 2) / 2 <= ti) ++r;
    int c = ti - r * (r + 1) / 2;
    m0 = c * BM;
    n0 = r * BN;
  } else if constexpr (EPI == EPI_GQK) {
    qk = (blockIdx.y == 12);
    if (qk) A = A2;  // inW^T (128 x 768)
    m0 = qk ? 0 : blockIdx.y * BM;
    n0 = blockIdx.x * BN;
  } else {
    m0 = blockIdx.y * BM;
    n0 = blockIdx.x * BN;
  }

  A += (size_t)z * az;
  Bt += (size_t)z * btz;
  out0 += (size_t)z * ozb;

  const int wm = (w >> 1) * 64;
  const int wn = (w & 1) * 64;
  const int quad = l >> 4;
  const int lr = quad * 4;
  const int lc = l & 15;

  f32x4 acc[4][4] = {};

  for (int ko = 0; ko < K; ko += BK) {
    stage_tile(A, K, m0, ko, As, w, l);
    stage_tile(Bt, K, n0, ko, Bs, w, l);
    __syncthreads();
#pragma unroll
    for (int kk = 0; kk < 2; ++kk) {
      short8 af[4], bfr[4];
#pragma unroll
      for (int i = 0; i < 4; ++i)
        af[i] = *(const short8*)&As[(wm + i * 16 + lc) * BK + kk * 32 + quad * 8];
#pragma unroll
      for (int j = 0; j < 4; ++j)
        bfr[j] = *(const short8*)&Bs[(wn + j * 16 + lc) * BK + kk * 32 + quad * 8];
#pragma unroll
      for (int i = 0; i < 4; ++i)
#pragma unroll
        for (int j = 0; j < 4; ++j)
          acc[i][j] = __builtin_amdgcn_mfma_f32_16x16x32_bf16(af[i], bfr[j], acc[i][j], 0, 0, 0);
    }
    __syncthreads();
  }

#pragma unroll
  for (int i = 0; i < 4; ++i) {
    const int gm = m0 + wm + i * 16 + lr;
#pragma unroll
    for (int j = 0; j < 4; ++j) {
      const int gn = n0 + wn + j * 16 + lc;
      f32x4 a = acc[i][j];
      if constexpr (EPI == EPI_VT) {
        // C = v (M=BS, N=I). Store vt[b][n][s], 4 consecutive s.
        float bn_ = f0[gn];
        us4 pk;
#pragma unroll
        for (int r = 0; r < 4; ++r) pk[r] = f2bf(silu_f(a[r] + bn_));
        size_t off = (size_t)(gm >> 11) * (1536 * 2048) + (size_t)gn * 2048 + (gm & 2047);
        *(us4*)((unsigned short*)out0 + off) = pk;
      } else if constexpr (EPI == EPI_GQK) {
        if (!qk) {
          // C = gate^T (M=I, N=BS).
          fl4 bv = *(const fl4*)&f0[gm];
          us4 pk;
#pragma unroll
          for (int r = 0; r < 4; ++r) pk[r] = f2bf(silu_f(a[r] + bv[r]));
          *(us4*)((unsigned short*)out0 + (size_t)gn * 1536 + gm) = pk;
        } else {
          // C = base^T (M=H=128, N=BS). q/k row-major [BS][128].
          fl4 bb = *(const fl4*)&f1[gm];
          fl4 qg = *(const fl4*)&f2[gm];
          fl4 qb = *(const fl4*)&f3[gm];
          fl4 kg = *(const fl4*)&f4[gm];
          fl4 kb = *(const fl4*)&f5[gm];
          us4 pq, pk2;
#pragma unroll
          for (int r = 0; r < 4; ++r) {
            float s = silu_f(a[r] + bb[r]);
            pq[r] = f2bf(s * qg[r] + qb[r]);
            pk2[r] = f2bf(s * kg[r] + kb[r]);
          }
          *(us4*)((unsigned short*)out1 + (size_t)gn * 128 + gm) = pq;
          *(us4*)((unsigned short*)out2 + (size_t)gn * 128 + gm) = pk2;
        }
      } else if constexpr (EPI == EPI_SCORES) {
        // C[m=s'][n=s] = k.q ; P[s][s'] = relu(C*scale + bias[s-s'])^2 if s'<=s else 0
        const float SCALE = 0.025515518153991442f;  // 1/sqrt(1536)
        us4 pk;
#pragma unroll
        for (int r = 0; r < 4; ++r) {
          int mm = gm + r;
          float v = 0.0f;
          if (mm <= gn) {
            float tt = fmaf(a[r], SCALE, bias_tab[gn - mm]);
            tt = fmaxf(tt, 0.0f);
            v = tt * tt;
          }
          pk[r] = f2bf(v);
        }
        *(us4*)((unsigned short*)out0 + (size_t)gn * 2048 + gm) = pk;
      } else {  // EPI_OUT: C = out^T (M=D=768, N=BS). d_out[gn][gm..gm+3] float4.
        fl4 ob = *(const fl4*)&f0[gm];
        fl4 res;
#pragma unroll
        for (int r = 0; r < 4; ++r) res[r] = a[r] + ob[r];
        *(fl4*)((float*)out0 + (size_t)gn * 768 + gm) = res;
      }
    }
  }
}

// Balanced causal og GEMM: og^T = vt @ P^T (elementwise * gate).
// 64x128 tiles; each block does n-tile pair (pair, 15-pair) -> 34 K-iters flat.
__global__ __launch_bounds__(256) void gemm_og(
    const unsigned short* __restrict__ Vt,    // [B][1536][2048]
    const unsigned short* __restrict__ P,     // [B][2048][2048]
    const unsigned short* __restrict__ gate,  // [B*2048][1536]
    unsigned short* __restrict__ og) {        // [B*2048][1536]
  __shared__ unsigned short As[64 * 64];
  __shared__ unsigned short Bs[128 * 64];
  const int t = threadIdx.x, l = t & 63, w = t >> 6;
  const int pair = blockIdx.x;     // 0..7
  const int m0 = blockIdx.y * 64;  // I tile
  const int z = blockIdx.z;
  const unsigned short* A = Vt + (size_t)z * 1536 * 2048;
  const unsigned short* B = P + (size_t)z * 2048 * 2048;
  const unsigned short* G = gate + (size_t)z * 2048 * 1536;
  unsigned short* O = og + (size_t)z * 2048 * 1536;
  const int wm = (w >> 1) * 32, wn = (w & 1) * 64;
  const int quad = l >> 4, lr = quad * 4, lc = l & 15;

#pragma unroll
  for (int pass = 0; pass < 2; ++pass) {
    const int nt = pass ? 15 - pair : pair;
    const int n0 = nt * 128;
    const int kend = n0 + 128;  // causal extent
    f32x4 acc[2][4] = {};
    for (int ko = 0; ko < kend; ko += 64) {
#pragma unroll
      for (int c = 0; c < 2; ++c) {  // A: 64x64
        int e = ((w * 2 + c) << 9) + l * 8;
        gl_lds(A + (size_t)(m0 + (e >> 6)) * 2048 + ko + (e & 63), As + e);
      }
#pragma unroll
      for (int c = 0; c < 4; ++c) {  // B: 128x64
        int e = ((w * 4 + c) << 9) + l * 8;
        gl_lds(B + (size_t)(n0 + (e >> 6)) * 2048 + ko + (e & 63), Bs + e);
      }
      __syncthreads();
#pragma unroll
      for (int kk = 0; kk < 2; ++kk) {
        short8 af[2], bfr[4];
#pragma unroll
        for (int i = 0; i < 2; ++i)
          af[i] = *(const short8*)&As[(wm + i * 16 + lc) * 64 + kk * 32 + quad * 8];
#pragma unroll
        for (int j = 0; j < 4; ++j)
          bfr[j] = *(const short8*)&Bs[(wn + j * 16 + lc) * 64 + kk * 32 + quad * 8];
#pragma unroll
        for (int i = 0; i < 2; ++i)
#pragma unroll
          for (int j = 0; j < 4; ++j)
            acc[i][j] = __builtin_amdgcn_mfma_f32_16x16x32_bf16(af[i], bfr[j], acc[i][j], 0, 0, 0);
      }
      __syncthreads();
    }
#pragma unroll
    for (int i = 0; i < 2; ++i) {
      const int gm = m0 + wm + i * 16 + lr;
#pragma unroll
      for (int j = 0; j < 4; ++j) {
        const int gn = n0 + wn + j * 16 + lc;
        us4 g4 = *(const us4*)&G[(size_t)gn * 1536 + gm];
        us4 pk;
#pragma unroll
        for (int r = 0; r < 4; ++r) pk[r] = f2bf(acc[i][j][r] * bf2f(g4[r]));
        *(us4*)&O[(size_t)gn * 1536 + gm] = pk;
      }
    }
  }
}

__global__ void cvt_bf16(const float* __restrict__ in, unsigned short* __restrict__ out, int n) {
  int i = (blockIdx.x * blockDim.x + threadIdx.x) * 4;
  if (i < n) {
    fl4 v = *(const fl4*)&in[i];
    us4 o;
#pragma unroll
    for (int r = 0; r < 4; ++r) o[r] = f2bf(v[r]);
    *(us4*)&out[i] = o;
  }
}

// 4 weight transposes in one launch; z selects matrix. out[n][k] = bf16(in[k][n]).
__global__ void transpose_cvt4(const float* __restrict__ s0, unsigned short* __restrict__ d0,
                               const float* __restrict__ s1, unsigned short* __restrict__ d1,
                               const float* __restrict__ s2, unsigned short* __restrict__ d2,
                               const float* __restrict__ s3, unsigned short* __restrict__ d3) {
  __shared__ float tile[32][33];
  const float* in;
  unsigned short* out;
  int K_, N_, bxm, bym;
  switch (blockIdx.z) {
    case 0: in = s0; out = d0; K_ = 768; N_ = 1536; bxm = 48; bym = 24; break;
    case 1: in = s1; out = d1; K_ = 768; N_ = 1536; bxm = 48; bym = 24; break;
    case 2: in = s2; out = d2; K_ = 768; N_ = 128;  bxm = 4;  bym = 24; break;
    default: in = s3; out = d3; K_ = 1536; N_ = 768; bxm = 24; bym = 48; break;
  }
  if ((int)blockIdx.x >= bxm || (int)blockIdx.y >= bym) return;
  int bn = blockIdx.x * 32, bk = blockIdx.y * 32;
  int tx = threadIdx.x, ty = threadIdx.y;
#pragma unroll
  for (int i2 = 0; i2 < 32; i2 += 8)
    tile[ty + i2][tx] = in[(size_t)(bk + ty + i2) * N_ + (bn + tx)];
  __syncthreads();
#pragma unroll
  for (int i2 = 0; i2 < 32; i2 += 8)
    out[(size_t)(bn + ty + i2) * K_ + (bk + tx)] = f2bf(tile[tx][ty + i2]);
}

// T5 relative position bias table: tab[d] = rel_emb[bucket(d)] * sqrt(128)
__global__ void build_bias(const float* __restrict__ rel_emb, float* __restrict__ tab) {
  int d = blockIdx.x * blockDim.x + threadIdx.x;
  if (d < 2048) {
    int bucket;
    if (d < 16) {
      bucket = d;
    } else {
      float n = (float)d;
      int vl = 16 + (int)((logf(n * 0.0625f) / logf(8.0f)) * 16.0f);
      bucket = vl < 31 ? vl : 31;
    }
    tab[d] = rel_emb[bucket] * 11.3137085f;
  }
}

extern "C" void kernel_launch(void* const* d_in, const int* in_sizes, int n_in,
                              void* d_out, int out_size, void* d_ws, size_t ws_size,
                              hipStream_t stream) {
  const float* x    = (const float*)d_in[0];
  const float* vW   = (const float*)d_in[1];
  const float* v_b  = (const float*)d_in[2];
  const float* gW   = (const float*)d_in[3];
  const float* g_b  = (const float*)d_in[4];
  const float* inW  = (const float*)d_in[5];
  const float* in_b = (const float*)d_in[6];
  const float* q_g  = (const float*)d_in[7];
  const float* q_be = (const float*)d_in[8];
  const float* k_g  = (const float*)d_in[9];
  const float* k_be = (const float*)d_in[10];
  const float* oW   = (const float*)d_in[11];
  const float* o_b  = (const float*)d_in[12];
  const float* rel  = (const float*)d_in[13];

  char* p = (char*)d_ws;
  auto alloc = [&](size_t bytes) -> char* {
    char* r = p;
    p += (bytes + 255) & ~(size_t)255;
    return r;
  };
  unsigned short* x_bf = (unsigned short*)alloc(8192ull * 768 * 2);
  unsigned short* vWt  = (unsigned short*)alloc(1536ull * 768 * 2);
  unsigned short* gWt  = (unsigned short*)alloc(1536ull * 768 * 2);
  unsigned short* inWt = (unsigned short*)alloc(128ull * 768 * 2);
  unsigned short* oWt  = (unsigned short*)alloc(768ull * 1536 * 2);
  unsigned short* wq   = (unsigned short*)alloc(8192ull * 128 * 2);
  unsigned short* wk   = (unsigned short*)alloc(8192ull * 128 * 2);
  unsigned short* vt   = (unsigned short*)alloc(4ull * 1536 * 2048 * 2);
  unsigned short* gate = (unsigned short*)alloc(8192ull * 1536 * 2);
  unsigned short* P    = (unsigned short*)alloc(4ull * 2048 * 2048 * 2);
  unsigned short* og   = (unsigned short*)alloc(8192ull * 1536 * 2);
  float* btab          = (float*)alloc(2048 * 4);

  cvt_bf16<<<dim3(6144), dim3(256), 0, stream>>>(x, x_bf, 8192 * 768);
  transpose_cvt4<<<dim3(48, 48, 4), dim3(32, 8), 0, stream>>>(vW, vWt, gW, gWt, inW, inWt, oW, oWt);
  build_bias<<<dim3(8), dim3(256), 0, stream>>>(rel, btab);

  // G1: v^T. A=x (8192x768), Bt=vW^T (1536x768). M=8192,N=1536.
  gemm_k<EPI_VT><<<dim3(12, 64, 1), 256, 0, stream>>>(
      x_bf, vWt, (char*)vt, nullptr, nullptr, v_b, nullptr, nullptr, nullptr, nullptr,
      nullptr, nullptr, nullptr, 768, 0, 0, 0);
  // G2+G3: gate^T (y<12) and base^T->q,k (y==12). A=gW^T / inW^T, Bt=x. N=8192.
  gemm_k<EPI_GQK><<<dim3(64, 13, 1), 256, 0, stream>>>(
      gWt, x_bf, (char*)gate, (char*)wq, (char*)wk, g_b, in_b, q_g, q_be, k_g, k_be,
      inWt, nullptr, 768, 0, 0, 0);
  // Scores: per batch, C = k@q^T (K=128) on lower-triangular tile set only.
  gemm_k<EPI_SCORES><<<dim3(136, 1, 4), 256, 0, stream>>>(
      wk, wq, (char*)P, nullptr, nullptr, nullptr, nullptr, nullptr, nullptr, nullptr, nullptr,
      nullptr, btab, 128, 2048ll * 128, 2048ll * 128, 2048ll * 2048 * 2);
  // OG: balanced causal (P@v)*gate.
  gemm_og<<<dim3(8, 24, 4), 256, 0, stream>>>(vt, P, gate, og);
  // G5: out^T. A=outW^T (768x1536), Bt=og (8192x1536). fp32 out + bias.
  gemm_k<EPI_OUT><<<dim3(64, 6, 1), 256, 0, stream>>>(
      oWt, og, (char*)d_out, nullptr, nullptr, o_b, nullptr, nullptr, nullptr, nullptr, nullptr,
      nullptr, nullptr, 1536, 0, 0, 0);
}

// Round 3
// 319.590 us; speedup vs baseline: 1.2278x; 1.0544x over previous
//
#include <hip/hip_runtime.h>

// GatedAttentionUnit: B=4, S=2048, D=768, I=1536, H=128, bf16 MFMA pipeline.
//  prep : cvt x->bf16; weight transposes into stacked [vWt;gWt;inWt]; bias table
//  G123 : one GEMM  C = x @ [vW gW inW]  (M=8192, N=3200, K=768), epilogue by region:
//           n<1536   -> vt[b][i][s] (transposed store, us4)
//           n<3072   -> gateT[i][bs] (us4)
//           else     -> q,k[bs][h]  (coalesced short stores)
//  SC   : P[b][s][s'] = relu(q.k/sqrt(I)+bias)^2 causal bf16, triangular tile grid
//  OG   : og[bs][i] = (P@v)*gate -- 128x128 tiles, XCD-aware LPT flat grid
//  GOUT : out[bs][d] = og@outW + ob (fp32)

typedef short short8 __attribute__((ext_vector_type(8)));
typedef float f32x4 __attribute__((ext_vector_type(4)));
typedef unsigned short us4 __attribute__((ext_vector_type(4)));
typedef float fl4 __attribute__((ext_vector_type(4)));

__device__ __forceinline__ unsigned short f2bf(float f) {
  unsigned u = __builtin_bit_cast(unsigned, f);
  u += 0x7FFFu + ((u >> 16) & 1u);
  return (unsigned short)(u >> 16);
}
__device__ __forceinline__ float bf2f(unsigned short b) {
  return __builtin_bit_cast(float, ((unsigned)b) << 16);
}
__device__ __forceinline__ float silu_f(float x) { return x / (1.0f + __expf(-x)); }

__device__ __forceinline__ void gl_lds(const unsigned short* gp, unsigned short* lp) {
  __builtin_amdgcn_global_load_lds((const __attribute__((address_space(1))) void*)gp,
                                   (__attribute__((address_space(3))) void*)lp, 16, 0, 0);
}

// global -> LDS async staging: 128x64 bf16 tile, 4 calls/wave x 16B/lane
__device__ __forceinline__ void stage_tile(const unsigned short* __restrict__ g,
                                           int row_stride, int r0, int ko,
                                           unsigned short* lds, int w, int l) {
#pragma unroll
  for (int c = 0; c < 4; ++c) {
    int e = ((w * 4 + c) << 9) + l * 8;
    gl_lds(g + (size_t)(r0 + (e >> 6)) * row_stride + (ko + (e & 63)), lds + e);
  }
}

// one 128x128 K-step: 2 kk x (8 ds_read_b128 + 16 MFMA)
__device__ __forceinline__ void mfma_step(const unsigned short* As, const unsigned short* Bs,
                                          f32x4 acc[4][4], int wm, int wn, int quad, int lc) {
#pragma unroll
  for (int kk = 0; kk < 2; ++kk) {
    short8 af[4], bfr[4];
#pragma unroll
    for (int i = 0; i < 4; ++i)
      af[i] = *(const short8*)&As[(wm + i * 16 + lc) * 64 + kk * 32 + quad * 8];
#pragma unroll
    for (int j = 0; j < 4; ++j)
      bfr[j] = *(const short8*)&Bs[(wn + j * 16 + lc) * 64 + kk * 32 + quad * 8];
#pragma unroll
    for (int i = 0; i < 4; ++i)
#pragma unroll
      for (int j = 0; j < 4; ++j)
        acc[i][j] = __builtin_amdgcn_mfma_f32_16x16x32_bf16(af[i], bfr[j], acc[i][j], 0, 0, 0);
  }
}

// ---------------- G123: x @ [vW gW inW] ----------------
__global__ __launch_bounds__(256) void g123_k(
    const unsigned short* __restrict__ X,    // 8192x768
    const unsigned short* __restrict__ Wst,  // 3200x768 stacked (row-major, = W^T)
    unsigned short* __restrict__ vt,         // [4][1536][2048]
    unsigned short* __restrict__ gateT,      // [1536][8192]
    unsigned short* __restrict__ wq,         // [8192][128]
    unsigned short* __restrict__ wk,         // [8192][128]
    const float* __restrict__ v_b, const float* __restrict__ g_b,
    const float* __restrict__ in_b, const float* __restrict__ q_g,
    const float* __restrict__ q_be, const float* __restrict__ k_g,
    const float* __restrict__ k_be) {
  __shared__ unsigned short As[128 * 64];
  __shared__ unsigned short Bs[128 * 64];
  const int t = threadIdx.x, l = t & 63, w = t >> 6;
  // XCD swizzle: id%8 -> XCD; cluster same-m (x-slab) blocks per XCD.
  const int id = blockIdx.x;
  const int xcd = id & 7, rest = id >> 3;
  const int n = rest % 25, m = (rest / 25) * 8 + xcd;
  const int m0 = m * 128, n0 = n * 128;
  const int wm = (w >> 1) * 64, wn = (w & 1) * 64;
  const int quad = l >> 4, lr = quad * 4, lc = l & 15;

  f32x4 acc[4][4] = {};
  for (int ko = 0; ko < 768; ko += 64) {
    stage_tile(X, 768, m0, ko, As, w, l);
    stage_tile(Wst, 768, n0, ko, Bs, w, l);
    __syncthreads();
    mfma_step(As, Bs, acc, wm, wn, quad, lc);
    __syncthreads();
  }

#pragma unroll
  for (int i = 0; i < 4; ++i) {
    const int gm = m0 + wm + i * 16 + lr;  // bs row
#pragma unroll
    for (int j = 0; j < 4; ++j) {
      const int gn = n0 + wn + j * 16 + lc;  // stacked col
      f32x4 a = acc[i][j];
      if (n0 < 1536) {  // v -> vt[b][i][s], 4 consecutive s
        float bv = v_b[gn];
        us4 pk;
#pragma unroll
        for (int r = 0; r < 4; ++r) pk[r] = f2bf(silu_f(a[r] + bv));
        size_t off = (size_t)(gm >> 11) * (1536 * 2048) + (size_t)gn * 2048 + (gm & 2047);
        *(us4*)&vt[off] = pk;
      } else if (n0 < 3072) {  // gateT[i][bs], 4 consecutive bs
        float bv = g_b[gn - 1536];
        us4 pk;
#pragma unroll
        for (int r = 0; r < 4; ++r) pk[r] = f2bf(silu_f(a[r] + bv));
        *(us4*)&gateT[(size_t)(gn - 1536) * 8192 + gm] = pk;
      } else {  // qk: coalesced short stores (lanes span h)
        int h = gn - 3072;
        float bb = in_b[h], qg = q_g[h], qb = q_be[h], kg = k_g[h], kb = k_be[h];
#pragma unroll
        for (int r = 0; r < 4; ++r) {
          float s = silu_f(a[r] + bb);
          wq[(size_t)(gm + r) * 128 + h] = f2bf(s * qg + qb);
          wk[(size_t)(gm + r) * 128 + h] = f2bf(s * kg + kb);
        }
      }
    }
  }
}

// ---------------- SC: scores -> P ----------------
__global__ __launch_bounds__(256) void scores_k(
    const unsigned short* __restrict__ wk, const unsigned short* __restrict__ wq,
    unsigned short* __restrict__ P, const float* __restrict__ btab) {
  __shared__ unsigned short As[128 * 64];
  __shared__ unsigned short Bs[128 * 64];
  const int t = threadIdx.x, l = t & 63, w = t >> 6;
  const int z = blockIdx.z;
  int ti = blockIdx.x;  // triangular decode: c <= r
  int r = (int)((sqrtf((float)(8 * ti + 1)) - 1.0f) * 0.5f);
  if ((r + 1) * (r + 2) / 2 <= ti) ++r;
  int c = ti - r * (r + 1) / 2;
  const int m0 = c * 128, n0 = r * 128;
  const unsigned short* A = wk + (size_t)z * 2048 * 128;
  const unsigned short* Bt = wq + (size_t)z * 2048 * 128;
  unsigned short* Pz = P + (size_t)z * 2048 * 2048;
  const int wm = (w >> 1) * 64, wn = (w & 1) * 64;
  const int quad = l >> 4, lr = quad * 4, lc = l & 15;

  f32x4 acc[4][4] = {};
  for (int ko = 0; ko < 128; ko += 64) {
    stage_tile(A, 128, m0, ko, As, w, l);
    stage_tile(Bt, 128, n0, ko, Bs, w, l);
    __syncthreads();
    mfma_step(As, Bs, acc, wm, wn, quad, lc);
    __syncthreads();
  }
  const float SCALE = 0.025515518153991442f;  // 1/sqrt(1536)
#pragma unroll
  for (int i = 0; i < 4; ++i) {
    const int gm = m0 + wm + i * 16 + lr;  // s'
#pragma unroll
    for (int j = 0; j < 4; ++j) {
      const int gn = n0 + wn + j * 16 + lc;  // s
      us4 pk;
#pragma unroll
      for (int r2 = 0; r2 < 4; ++r2) {
        int mm = gm + r2;
        float v = 0.0f;
        if (mm <= gn) {
          float tt = fmaf(acc[i][j][r2], SCALE, btab[gn - mm]);
          tt = fmaxf(tt, 0.0f);
          v = tt * tt;
        }
        pk[r2] = f2bf(v);
      }
      *(us4*)&Pz[(size_t)gn * 2048 + gm] = pk;
    }
  }
}

// ---------------- OG: (P@v)*gate, XCD-aware LPT ----------------
__global__ __launch_bounds__(256) void og_k(
    const unsigned short* __restrict__ Vt,     // [4][1536][2048]
    const unsigned short* __restrict__ P,      // [4][2048][2048]
    const unsigned short* __restrict__ gateT,  // [1536][8192]
    unsigned short* __restrict__ og) {         // [8192][1536]
  __shared__ unsigned short As[128 * 64];
  __shared__ unsigned short Bs[128 * 64];
  const int t = threadIdx.x, l = t & 63, w = t >> 6;
  // id%8 -> XCD. Each XCD: one z, balanced nt half-set (136 iters x 12 m), heavy first.
  const int id = blockIdx.x;
  const int bblk = id / 96, rr = id % 96;
  const int xcd = rr & 7, mi = rr >> 3;
  const int half = xcd >> 2, z = xcd & 3;
  const int nt = 15 - 2 * bblk - (half ^ (bblk & 1));
  const int m0 = mi * 128;         // I tile
  const int n0 = nt * 128;         // S tile
  const int kend = n0 + 128;       // causal extent over S'
  const unsigned short* A = Vt + (size_t)z * 1536 * 2048;
  const unsigned short* B = P + (size_t)z * 2048 * 2048;
  const int wm = (w >> 1) * 64, wn = (w & 1) * 64;
  const int quad = l >> 4, lr = quad * 4, lc = l & 15;

  f32x4 acc[4][4] = {};
  for (int ko = 0; ko < kend; ko += 64) {
    stage_tile(A, 2048, m0, ko, As, w, l);
    stage_tile(B, 2048, n0, ko, Bs, w, l);
    __syncthreads();
    mfma_step(As, Bs, acc, wm, wn, quad, lc);
    __syncthreads();
  }
#pragma unroll
  for (int i = 0; i < 4; ++i) {
    const int gm = m0 + wm + i * 16 + lr;  // i
#pragma unroll
    for (int j = 0; j < 4; ++j) {
      const int gn = n0 + wn + j * 16 + lc;  // s
      us4 pk;
#pragma unroll
      for (int r2 = 0; r2 < 4; ++r2) {
        float g = bf2f(gateT[(size_t)(gm + r2) * 8192 + z * 2048 + gn]);
        pk[r2] = f2bf(acc[i][j][r2] * g);
      }
      *(us4*)&og[((size_t)z * 2048 + gn) * 1536 + gm] = pk;
    }
  }
}

// ---------------- GOUT: og @ outW + ob ----------------
__global__ __launch_bounds__(256) void gout_k(
    const unsigned short* __restrict__ A,   // oWt 768x1536
    const unsigned short* __restrict__ Bt,  // og 8192x1536
    float* __restrict__ out, const float* __restrict__ o_b) {
  __shared__ unsigned short As[128 * 64];
  __shared__ unsigned short Bs[128 * 64];
  const int t = threadIdx.x, l = t & 63, w = t >> 6;
  const int id = blockIdx.x;
  const int xcd = id & 7, rest = id >> 3;
  const int m = rest % 6, n = (rest / 6) * 8 + xcd;
  const int m0 = m * 128, n0 = n * 128;
  const int wm = (w >> 1) * 64, wn = (w & 1) * 64;
  const int quad = l >> 4, lr = quad * 4, lc = l & 15;

  f32x4 acc[4][4] = {};
  for (int ko = 0; ko < 1536; ko += 64) {
    stage_tile(A, 1536, m0, ko, As, w, l);
    stage_tile(Bt, 1536, n0, ko, Bs, w, l);
    __syncthreads();
    mfma_step(As, Bs, acc, wm, wn, quad, lc);
    __syncthreads();
  }
#pragma unroll
  for (int i = 0; i < 4; ++i) {
    const int gm = m0 + wm + i * 16 + lr;  // d
#pragma unroll
    for (int j = 0; j < 4; ++j) {
      const int gn = n0 + wn + j * 16 + lc;  // bs
      fl4 ob = *(const fl4*)&o_b[gm];
      fl4 res;
#pragma unroll
      for (int r2 = 0; r2 < 4; ++r2) res[r2] = acc[i][j][r2] + ob[r2];
      *(fl4*)&out[(size_t)gn * 768 + gm] = res;
    }
  }
}

// ---------------- prep ----------------
__global__ void cvt_bf16(const float* __restrict__ in, unsigned short* __restrict__ out, int n) {
  int i = (blockIdx.x * blockDim.x + threadIdx.x) * 4;
  if (i < n) {
    fl4 v = *(const fl4*)&in[i];
    us4 o;
#pragma unroll
    for (int r = 0; r < 4; ++r) o[r] = f2bf(v[r]);
    *(us4*)&out[i] = o;
  }
}

__global__ void transpose_cvt4(const float* __restrict__ s0, unsigned short* __restrict__ d0,
                               const float* __restrict__ s1, unsigned short* __restrict__ d1,
                               const float* __restrict__ s2, unsigned short* __restrict__ d2,
                               const float* __restrict__ s3, unsigned short* __restrict__ d3) {
  __shared__ float tile[32][33];
  const float* in;
  unsigned short* out;
  int K_, N_, bxm, bym;
  switch (blockIdx.z) {
    case 0: in = s0; out = d0; K_ = 768; N_ = 1536; bxm = 48; bym = 24; break;
    case 1: in = s1; out = d1; K_ = 768; N_ = 1536; bxm = 48; bym = 24; break;
    case 2: in = s2; out = d2; K_ = 768; N_ = 128;  bxm = 4;  bym = 24; break;
    default: in = s3; out = d3; K_ = 1536; N_ = 768; bxm = 24; bym = 48; break;
  }
  if ((int)blockIdx.x >= bxm || (int)blockIdx.y >= bym) return;
  int bn = blockIdx.x * 32, bk = blockIdx.y * 32;
  int tx = threadIdx.x, ty = threadIdx.y;
#pragma unroll
  for (int i2 = 0; i2 < 32; i2 += 8)
    tile[ty + i2][tx] = in[(size_t)(bk + ty + i2) * N_ + (bn + tx)];
  __syncthreads();
#pragma unroll
  for (int i2 = 0; i2 < 32; i2 += 8)
    out[(size_t)(bn + ty + i2) * K_ + (bk + tx)] = f2bf(tile[tx][ty + i2]);
}

__global__ void build_bias(const float* __restrict__ rel_emb, float* __restrict__ tab) {
  int d = blockIdx.x * blockDim.x + threadIdx.x;
  if (d < 2048) {
    int bucket;
    if (d < 16) {
      bucket = d;
    } else {
      float n = (float)d;
      int vl = 16 + (int)((logf(n * 0.0625f) / logf(8.0f)) * 16.0f);
      bucket = vl < 31 ? vl : 31;
    }
    tab[d] = rel_emb[bucket] * 11.3137085f;
  }
}

extern "C" void kernel_launch(void* const* d_in, const int* in_sizes, int n_in,
                              void* d_out, int out_size, void* d_ws, size_t ws_size,
                              hipStream_t stream) {
  const float* x    = (const float*)d_in[0];
  const float* vW   = (const float*)d_in[1];
  const float* v_b  = (const float*)d_in[2];
  const float* gW   = (const float*)d_in[3];
  const float* g_b  = (const float*)d_in[4];
  const float* inW  = (const float*)d_in[5];
  const float* in_b = (const float*)d_in[6];
  const float* q_g  = (const float*)d_in[7];
  const float* q_be = (const float*)d_in[8];
  const float* k_g  = (const float*)d_in[9];
  const float* k_be = (const float*)d_in[10];
  const float* oW   = (const float*)d_in[11];
  const float* o_b  = (const float*)d_in[12];
  const float* rel  = (const float*)d_in[13];

  char* p = (char*)d_ws;
  auto alloc = [&](size_t bytes) -> char* {
    char* r = p;
    p += (bytes + 255) & ~(size_t)255;
    return r;
  };
  unsigned short* x_bf   = (unsigned short*)alloc(8192ull * 768 * 2);
  unsigned short* wstack = (unsigned short*)alloc(3200ull * 768 * 2);  // [vWt;gWt;inWt]
  unsigned short* vWt  = wstack;
  unsigned short* gWt  = wstack + 1536ull * 768;
  unsigned short* inWt = wstack + 3072ull * 768;
  unsigned short* oWt  = (unsigned short*)alloc(768ull * 1536 * 2);
  unsigned short* wq   = (unsigned short*)alloc(8192ull * 128 * 2);
  unsigned short* wk   = (unsigned short*)alloc(8192ull * 128 * 2);
  unsigned short* vt   = (unsigned short*)alloc(4ull * 1536 * 2048 * 2);
  unsigned short* gateT= (unsigned short*)alloc(1536ull * 8192 * 2);
  unsigned short* P    = (unsigned short*)alloc(4ull * 2048 * 2048 * 2);
  unsigned short* og   = (unsigned short*)alloc(8192ull * 1536 * 2);
  float* btab          = (float*)alloc(2048 * 4);

  cvt_bf16<<<dim3(6144), dim3(256), 0, stream>>>(x, x_bf, 8192 * 768);
  transpose_cvt4<<<dim3(48, 48, 4), dim3(32, 8), 0, stream>>>(vW, vWt, gW, gWt, inW, inWt, oW, oWt);
  build_bias<<<dim3(8), dim3(256), 0, stream>>>(rel, btab);

  g123_k<<<dim3(1600), 256, 0, stream>>>(x_bf, wstack, vt, gateT, wq, wk,
                                         v_b, g_b, in_b, q_g, q_be, k_g, k_be);
  scores_k<<<dim3(136, 1, 4), 256, 0, stream>>>(wk, wq, P, btab);
  og_k<<<dim3(768), 256, 0, stream>>>(vt, P, gateT, og);
  gout_k<<<dim3(384), 256, 0, stream>>>(oWt, og, (float*)d_out, o_b);
}